// Round 8
// baseline (674.612 us; speedup 1.0000x reference)
//
#include <hip/hip_runtime.h>
#include <hip/hip_bf16.h>

#define HID 128
#define N_GRAPHS 64
#define NBKT 48          // dst>>10 clamped to 47; 48 % 8 == 0 for XCD affinity

// ---------------------------------------------------------------------------
// 1) degree init (self-loop counts as 1) + zero bucket counters
__global__ void init_deg_kernel(int* __restrict__ deg, int* __restrict__ bcnt, int n) {
    int i = blockIdx.x * 256 + threadIdx.x;
    if (i < n) deg[i] = 1;
    if (i < NBKT) bcnt[i] = 0;
}

// 2) count in-degrees + per-bucket edge counts (LDS-aggregated)
__global__ __launch_bounds__(256) void count_kernel(const int* __restrict__ dst,
                                                    int* __restrict__ deg,
                                                    int* __restrict__ bcnt, int E) {
    __shared__ int lb[NBKT];
    int t = threadIdx.x;
    if (t < NBKT) lb[t] = 0;
    __syncthreads();
    int e = blockIdx.x * 256 + t;
    if (e < E) {
        int d = dst[e];
        atomicAdd(&deg[d], 1);
        int b = d >> 10; if (b > NBKT - 1) b = NBKT - 1;
        atomicAdd(&lb[b], 1);
    }
    __syncthreads();
    if (t < NBKT && lb[t]) atomicAdd(&bcnt[t], lb[t]);
}

// 3a) per-block partial sums of deg
__global__ __launch_bounds__(256) void scan_partial_kernel(const int* __restrict__ deg,
                                                           int* __restrict__ bsum, int n) {
    __shared__ int red[256];
    int t = threadIdx.x;
    int i = blockIdx.x * 256 + t;
    red[t] = (i < n) ? deg[i] : 0;
    __syncthreads();
#pragma unroll
    for (int s = 128; s > 0; s >>= 1) {
        if (t < s) red[t] += red[t + s];
        __syncthreads();
    }
    if (t == 0) bsum[blockIdx.x] = red[0];
}

// 3b) single-block exclusive scan of block sums (nb <= 256)
__global__ __launch_bounds__(256) void scan_bsum_kernel(const int* __restrict__ bsum,
                                                        int* __restrict__ boff,
                                                        int* __restrict__ row_ptr,
                                                        int nb, int n) {
    __shared__ int arr[256];
    int t = threadIdx.x;
    int own = (t < nb) ? bsum[t] : 0;
    arr[t] = own;
    __syncthreads();
#pragma unroll
    for (int off = 1; off < 256; off <<= 1) {
        int v = arr[t];
        int add = (t >= off) ? arr[t - off] : 0;
        __syncthreads();
        arr[t] = v + add;
        __syncthreads();
    }
    if (t < nb) boff[t] = arr[t] - own;
    if (t == 255) row_ptr[n] = arr[255];
}

// 3c) emit row_ptr/cursor/dinv
__global__ __launch_bounds__(256) void scan_emit_kernel(const int* __restrict__ deg,
                                                        const int* __restrict__ boff,
                                                        int* __restrict__ row_ptr,
                                                        int* __restrict__ cursor,
                                                        float* __restrict__ dinv, int n) {
    __shared__ int arr[256];
    int t = threadIdx.x;
    int i = blockIdx.x * 256 + t;
    int d = (i < n) ? deg[i] : 0;
    arr[t] = d;
    __syncthreads();
#pragma unroll
    for (int off = 1; off < 256; off <<= 1) {
        int v = arr[t];
        int add = (t >= off) ? arr[t - off] : 0;
        __syncthreads();
        arr[t] = v + add;
        __syncthreads();
    }
    if (i < n) {
        int pos = boff[blockIdx.x] + arr[t] - d;
        row_ptr[i] = pos;
        cursor[i] = pos;
        dinv[i] = rsqrtf((float)d);
    }
}

// 3d) bucket base offsets (serial over 48 values) + init write cursors
__global__ void bucket_scan_kernel(const int* __restrict__ bcnt,
                                   int* __restrict__ bbase,
                                   int* __restrict__ gcur) {
    if (threadIdx.x == 0) {
        int run = 0;
        for (int b = 0; b < NBKT; ++b) {
            bbase[b] = run; gcur[b] = run; run += bcnt[b];
        }
    }
}

// 4a) phase A: scatter edges into dst-buckets, batch-ranked via LDS so each
//     bucket gets a run of consecutive slots per batch (write-combining friendly)
__global__ __launch_bounds__(256) void bucket_scatter_kernel(const int* __restrict__ src,
                                                             const int* __restrict__ dst,
                                                             int* __restrict__ gcur,
                                                             int2* __restrict__ bucket, int E) {
    __shared__ int bhist[NBKT];
    __shared__ int boffL[NBKT];
    int t = threadIdx.x;
    for (int base = blockIdx.x * 256; base < E; base += gridDim.x * 256) {
        if (t < NBKT) bhist[t] = 0;
        __syncthreads();
        int e = base + t;
        int s = 0, d = 0, b = 0, c = 0, valid = (e < E);
        if (valid) {
            s = src[e]; d = dst[e];
            b = d >> 10; if (b > NBKT - 1) b = NBKT - 1;
            c = atomicAdd(&bhist[b], 1);
        }
        __syncthreads();
        if (t < NBKT) {
            int h = bhist[t];
            boffL[t] = h ? atomicAdd(&gcur[t], h) : 0;
        }
        __syncthreads();
        if (valid) bucket[boffL[b] + c] = make_int2(s, d);
        __syncthreads();
    }
}

// 4b) phase B: per-bucket CSR fill. XCD-affinity: all 8 sub-blocks of bucket b
//     have blockIdx % 8 == b % 8, keeping the bucket's col region in one L2.
__global__ __launch_bounds__(256) void bucket_fill_kernel(const int2* __restrict__ bucket,
                                                          const int* __restrict__ bbase,
                                                          int* __restrict__ cursor,
                                                          int* __restrict__ col, int E) {
    int lin = blockIdx.x;            // 0..383
    int c8 = lin & 7;
    int q = lin >> 3;                // 0..47
    int b = c8 + 8 * (q % (NBKT / 8));   // bucket, b%8 == c8
    int sub = q / (NBKT / 8);            // 0..7
    int start = bbase[b];
    int end = (b == NBKT - 1) ? E : bbase[b + 1];
    int idx = sub * 256 + threadIdx.x;   // 0..2047
    for (int i = start + idx; i < end; i += 2048) {
        int2 sd = bucket[i];
        int pos = atomicAdd(&cursor[sd.y], 1);
        col[pos] = sd.x;
    }
}

// 4c) self-loops: last free slot of each row (all edge fills complete)
__global__ void loop_fill_kernel(const int* __restrict__ cursor,
                                 int* __restrict__ col, int n) {
    int i = blockIdx.x * 256 + threadIdx.x;
    if (i < n) col[cursor[i]] = i;
}

// 5) GEMM: out[r][:] = dinv[r] * (A[r][:] @ W)
//    128x128 tile, 8x8 per thread, BK=32, A staged transposed in LDS.
//    launch_bounds (256,2): no VGPR cap at 128 -> no forced spill.
__global__ __launch_bounds__(256, 2) void gemm_scale_kernel(const float* __restrict__ A,
                                                            const float* __restrict__ W,
                                                            const float* __restrict__ dinv,
                                                            float* __restrict__ out, int M) {
    __shared__ float sAT[32][132];
    __shared__ float sW[32][132];
    int tid = threadIdx.x;
    int row0 = blockIdx.x * 128;
    int ty = tid >> 4, tx = tid & 15;
    int r0 = ty * 8;
    int cl = tx * 4;
    int ch = 64 + tx * 4;

    float acc[8][8];
#pragma unroll
    for (int i = 0; i < 8; ++i)
#pragma unroll
        for (int j = 0; j < 8; ++j) acc[i][j] = 0.f;

    for (int kc = 0; kc < 128; kc += 32) {
#pragma unroll
        for (int p = 0; p < 4; ++p) {
            int idx = tid + p * 256;
            int k = idx >> 5, c4 = idx & 31;
            float4 v = *(const float4*)(W + (size_t)(kc + k) * 128 + c4 * 4);
            *(float4*)&sW[k][c4 * 4] = v;
        }
#pragma unroll
        for (int p = 0; p < 4; ++p) {
            int idx = tid + p * 256;
            int r = idx >> 3, c4 = idx & 7;
            float4 v = make_float4(0.f, 0.f, 0.f, 0.f);
            if (row0 + r < M) v = *(const float4*)(A + (size_t)(row0 + r) * 128 + kc + c4 * 4);
            sAT[c4 * 4 + 0][r] = v.x;
            sAT[c4 * 4 + 1][r] = v.y;
            sAT[c4 * 4 + 2][r] = v.z;
            sAT[c4 * 4 + 3][r] = v.w;
        }
        __syncthreads();

#pragma unroll 4
        for (int k = 0; k < 32; ++k) {
            float4 a0 = *(float4*)&sAT[k][r0];
            float4 a1 = *(float4*)&sAT[k][r0 + 4];
            float4 w0 = *(float4*)&sW[k][cl];
            float4 w1 = *(float4*)&sW[k][ch];
            float a[8] = {a0.x, a0.y, a0.z, a0.w, a1.x, a1.y, a1.z, a1.w};
            float w[8] = {w0.x, w0.y, w0.z, w0.w, w1.x, w1.y, w1.z, w1.w};
#pragma unroll
            for (int i = 0; i < 8; ++i)
#pragma unroll
                for (int j = 0; j < 8; ++j)
                    acc[i][j] += a[i] * w[j];
        }
        __syncthreads();
    }

#pragma unroll
    for (int i = 0; i < 8; ++i) {
        int r = row0 + r0 + i;
        if (r < M) {
            float dv = dinv[r];
            float4 lo, hi;
            lo.x = acc[i][0] * dv; lo.y = acc[i][1] * dv;
            lo.z = acc[i][2] * dv; lo.w = acc[i][3] * dv;
            hi.x = acc[i][4] * dv; hi.y = acc[i][5] * dv;
            hi.z = acc[i][6] * dv; hi.w = acc[i][7] * dv;
            *(float4*)(out + (size_t)r * 128 + cl) = lo;
            *(float4*)(out + (size_t)r * 128 + ch) = hi;
        }
    }
}

// 6) aggregation: out[v][:] = relu(dinv[v] * sum_{s in N(v)} hw[s][:] + b)
__global__ __launch_bounds__(256) void aggregate_kernel(const float* __restrict__ hw,
                                                        const int* __restrict__ row_ptr,
                                                        const int* __restrict__ col,
                                                        const float* __restrict__ dinv,
                                                        const float* __restrict__ bias,
                                                        float* __restrict__ out, int n) {
    int tid = threadIdx.x;
    int v = blockIdx.x * 8 + (tid >> 5);
    if (v >= n) return;
    int j = (tid & 31) * 4;
    int p0 = row_ptr[v], p1 = row_ptr[v + 1];
    float4 acc = make_float4(0.f, 0.f, 0.f, 0.f);
    int p = p0;
    for (; p + 3 < p1; p += 4) {
        int s0 = col[p], s1 = col[p + 1], s2 = col[p + 2], s3 = col[p + 3];
        float4 a = *(const float4*)(hw + (size_t)s0 * 128 + j);
        float4 b = *(const float4*)(hw + (size_t)s1 * 128 + j);
        float4 c = *(const float4*)(hw + (size_t)s2 * 128 + j);
        float4 d = *(const float4*)(hw + (size_t)s3 * 128 + j);
        acc.x += (a.x + b.x) + (c.x + d.x);
        acc.y += (a.y + b.y) + (c.y + d.y);
        acc.z += (a.z + b.z) + (c.z + d.z);
        acc.w += (a.w + b.w) + (c.w + d.w);
    }
    for (; p < p1; ++p) {
        int s0 = col[p];
        float4 a = *(const float4*)(hw + (size_t)s0 * 128 + j);
        acc.x += a.x; acc.y += a.y; acc.z += a.z; acc.w += a.w;
    }
    float dv = dinv[v];
    float4 bb = *(const float4*)(bias + j);
    float4 o;
    o.x = fmaxf(acc.x * dv + bb.x, 0.f);
    o.y = fmaxf(acc.y * dv + bb.y, 0.f);
    o.z = fmaxf(acc.z * dv + bb.z, 0.f);
    o.w = fmaxf(acc.w * dv + bb.w, 0.f);
    *(float4*)(out + (size_t)v * 128 + j) = o;
}

// 7) graph boundary detection (batch sorted)
__global__ void boundary_kernel(const int* __restrict__ batch, int* __restrict__ start, int n) {
    int i = blockIdx.x * 256 + threadIdx.x;
    if (i >= n) return;
    int b = batch[i];
    int pb = (i > 0) ? batch[i - 1] : -1;
    if (b != pb) {
        for (int g = pb + 1; g <= b; ++g) start[g] = i;
    }
    if (i == n - 1) {
        for (int g = b + 1; g <= N_GRAPHS; ++g) start[g] = n;
    }
}

// 8) pooled mean per graph
__global__ __launch_bounds__(256) void pool_reduce_kernel(const float* __restrict__ h,
                                                          const int* __restrict__ start,
                                                          float* __restrict__ pooled) {
    __shared__ float part[8][128];
    int g = blockIdx.x;
    int s = start[g], e = start[g + 1];
    int tid = threadIdx.x;
    int grp = tid >> 5;
    int j = (tid & 31) * 4;
    float4 acc = make_float4(0.f, 0.f, 0.f, 0.f);
    for (int v = s + grp; v < e; v += 8) {
        float4 a = *(const float4*)(h + (size_t)v * 128 + j);
        acc.x += a.x; acc.y += a.y; acc.z += a.z; acc.w += a.w;
    }
    *(float4*)&part[grp][j] = acc;
    __syncthreads();
    if (tid < 128) {
        float sum = 0.f;
#pragma unroll
        for (int k = 0; k < 8; ++k) sum += part[k][tid];
        int cntv = e - s; if (cntv < 1) cntv = 1;
        pooled[g * 128 + tid] = sum / (float)cntv;
    }
}

// 9) final MLP
__global__ __launch_bounds__(256) void mlp_kernel(const float* __restrict__ pooled_g,
                                                  const float* __restrict__ W1,
                                                  const float* __restrict__ b1,
                                                  const float* __restrict__ W2,
                                                  const float* __restrict__ b2,
                                                  float* __restrict__ out) {
    __shared__ float pooled[64][128];
    __shared__ float h1[64][64];
    int tid = threadIdx.x;
    for (int i = tid; i < 64 * 128; i += 256) pooled[i >> 7][i & 127] = pooled_g[i];
    __syncthreads();
    for (int i = tid; i < 64 * 64; i += 256) {
        int g = i >> 6, j = i & 63;
        float acc = b1[j];
        for (int k = 0; k < 128; ++k) acc += pooled[g][k] * W1[k * 64 + j];
        h1[g][j] = fmaxf(acc, 0.f);
    }
    __syncthreads();
    if (tid < 128) {
        int g = tid >> 1, c = tid & 1;
        float acc = b2[c];
        for (int jj = 0; jj < 64; ++jj) acc += h1[g][jj] * W2[jj * 2 + c];
        out[tid] = acc;
    }
}

// ---------------------------------------------------------------------------
extern "C" void kernel_launch(void* const* d_in, const int* in_sizes, int n_in,
                              void* d_out, int out_size, void* d_ws, size_t ws_size,
                              hipStream_t stream) {
    const float* x    = (const float*)d_in[0];
    const int*   ei   = (const int*)d_in[1];
    const int*   batch= (const int*)d_in[2];
    const float* W0   = (const float*)d_in[3];
    const float* b0   = (const float*)d_in[4];
    const float* Ws   = (const float*)d_in[5];
    const float* bs   = (const float*)d_in[6];
    const float* W1   = (const float*)d_in[7];
    const float* b1   = (const float*)d_in[8];
    const float* W2   = (const float*)d_in[9];
    const float* b2   = (const float*)d_in[10];
    float* out = (float*)d_out;

    const int n  = in_sizes[0] / HID;      // 50000
    const int E  = in_sizes[1] / 2;        // 800000
    const int EN = E + n;                  // 850000
    const int* src = ei;
    const int* dst = ei + E;
    const int nb = (n + 255) / 256;        // 196

    char* ws = (char*)d_ws;
    size_t off = 0;
    auto alloc = [&](size_t bytes) { void* p = ws + off; off = (off + bytes + 255) & ~(size_t)255; return p; };
    float* bufA   = (float*)alloc((size_t)n * HID * 4);
    float* bufB   = (float*)alloc((size_t)n * HID * 4);
    float* dinv   = (float*)alloc((size_t)n * 4);
    int*   row_ptr= (int*)  alloc((size_t)(n + 1) * 4);
    int*   cursor = (int*)  alloc((size_t)n * 4);
    int*   deg    = (int*)  alloc((size_t)n * 4);
    int*   col    = (int*)  alloc((size_t)EN * 4);
    int2*  bucket = (int2*) alloc((size_t)E * 8);
    int*   bcnt   = (int*)  alloc(NBKT * 4);
    int*   bbase  = (int*)  alloc(NBKT * 4);
    int*   gcur   = (int*)  alloc(NBKT * 4);
    int*   bsum   = (int*)  alloc((size_t)nb * 4);
    int*   boff   = (int*)  alloc((size_t)nb * 4);
    int*   gstart = (int*)  alloc((N_GRAPHS + 1) * 4);
    float* pooled = (float*)alloc(N_GRAPHS * 128 * 4);
    (void)ws_size; (void)n_in; (void)out_size;

    // --- build normalized CSR ---
    init_deg_kernel<<<nb, 256, 0, stream>>>(deg, bcnt, n);
    count_kernel<<<(E + 255) / 256, 256, 0, stream>>>(dst, deg, bcnt, E);
    scan_partial_kernel<<<nb, 256, 0, stream>>>(deg, bsum, n);
    scan_bsum_kernel<<<1, 256, 0, stream>>>(bsum, boff, row_ptr, nb, n);
    scan_emit_kernel<<<nb, 256, 0, stream>>>(deg, boff, row_ptr, cursor, dinv, n);
    bucket_scan_kernel<<<1, 64, 0, stream>>>(bcnt, bbase, gcur);
    bucket_scatter_kernel<<<512, 256, 0, stream>>>(src, dst, gcur, bucket, E);
    bucket_fill_kernel<<<NBKT * 8, 256, 0, stream>>>(bucket, bbase, cursor, col, E);
    loop_fill_kernel<<<nb, 256, 0, stream>>>(cursor, col, n);
    boundary_kernel<<<nb, 256, 0, stream>>>(batch, gstart, n);

    const int gemm_grid = (n + 127) / 128;
    const int node_grid = (n + 7) / 8;

    // --- layer 0 ---
    gemm_scale_kernel<<<gemm_grid, 256, 0, stream>>>(x, W0, dinv, bufB, n);
    aggregate_kernel<<<node_grid, 256, 0, stream>>>(bufB, row_ptr, col, dinv, b0, bufA, n);
    // --- layers 1..3 ---
    for (int l = 0; l < 3; ++l) {
        gemm_scale_kernel<<<gemm_grid, 256, 0, stream>>>(bufA, Ws + (size_t)l * HID * HID, dinv, bufB, n);
        aggregate_kernel<<<node_grid, 256, 0, stream>>>(bufB, row_ptr, col, dinv, bs + (size_t)l * HID, bufA, n);
    }

    // --- pooling + MLP ---
    pool_reduce_kernel<<<N_GRAPHS, 256, 0, stream>>>(bufA, gstart, pooled);
    mlp_kernel<<<1, 256, 0, stream>>>(pooled, W1, b1, W2, b2, out);
}

// Round 9
// 509.603 us; speedup vs baseline: 1.3238x; 1.3238x over previous
//
#include <hip/hip_runtime.h>
#include <hip/hip_bf16.h>
#include <hip/hip_fp16.h>

#define HID 128
#define N_GRAPHS 64

// ---------------------------------------------------------------------------
// 1) degree init (self-loop counts as 1)
__global__ void init_deg_kernel(int* __restrict__ deg, int n) {
    int i = blockIdx.x * 256 + threadIdx.x;
    if (i < n) deg[i] = 1;
}

// 2) count in-degrees (simple global atomics; LDS-histogram variant regressed)
__global__ void count_kernel(const int* __restrict__ dst, int* __restrict__ deg, int E) {
    int e = blockIdx.x * 256 + threadIdx.x;
    if (e < E) atomicAdd(&deg[dst[e]], 1);
}

// 3a) per-block partial sums of deg
__global__ __launch_bounds__(256) void scan_partial_kernel(const int* __restrict__ deg,
                                                           int* __restrict__ bsum, int n) {
    __shared__ int red[256];
    int t = threadIdx.x;
    int i = blockIdx.x * 256 + t;
    red[t] = (i < n) ? deg[i] : 0;
    __syncthreads();
#pragma unroll
    for (int s = 128; s > 0; s >>= 1) {
        if (t < s) red[t] += red[t + s];
        __syncthreads();
    }
    if (t == 0) bsum[blockIdx.x] = red[0];
}

// 3b) single-block exclusive scan of block sums (nb <= 256)
__global__ __launch_bounds__(256) void scan_bsum_kernel(const int* __restrict__ bsum,
                                                        int* __restrict__ boff,
                                                        int* __restrict__ row_ptr,
                                                        int nb, int n) {
    __shared__ int arr[256];
    int t = threadIdx.x;
    int own = (t < nb) ? bsum[t] : 0;
    arr[t] = own;
    __syncthreads();
#pragma unroll
    for (int off = 1; off < 256; off <<= 1) {
        int v = arr[t];
        int add = (t >= off) ? arr[t - off] : 0;
        __syncthreads();
        arr[t] = v + add;
        __syncthreads();
    }
    if (t < nb) boff[t] = arr[t] - own;
    if (t == 255) row_ptr[n] = arr[255];
}

// 3c) emit row_ptr/cursor/dinv
__global__ __launch_bounds__(256) void scan_emit_kernel(const int* __restrict__ deg,
                                                        const int* __restrict__ boff,
                                                        int* __restrict__ row_ptr,
                                                        int* __restrict__ cursor,
                                                        float* __restrict__ dinv, int n) {
    __shared__ int arr[256];
    int t = threadIdx.x;
    int i = blockIdx.x * 256 + t;
    int d = (i < n) ? deg[i] : 0;
    arr[t] = d;
    __syncthreads();
#pragma unroll
    for (int off = 1; off < 256; off <<= 1) {
        int v = arr[t];
        int add = (t >= off) ? arr[t - off] : 0;
        __syncthreads();
        arr[t] = v + add;
        __syncthreads();
    }
    if (i < n) {
        int pos = boff[blockIdx.x] + arr[t] - d;
        row_ptr[i] = pos;
        cursor[i] = pos;
        dinv[i] = rsqrtf((float)d);
    }
}

// 4) fill CSR columns (edges + implicit self-loops)
__global__ void fill_kernel(const int* __restrict__ src, const int* __restrict__ dst,
                            int* __restrict__ cursor, int* __restrict__ col,
                            int E, int EN) {
    int e = blockIdx.x * 256 + threadIdx.x;
    if (e >= EN) return;
    int s, d;
    if (e < E) { s = src[e]; d = dst[e]; }
    else       { s = e - E; d = s; }
    int pos = atomicAdd(&cursor[d], 1);
    col[pos] = s;
}

// 5) GEMM: hw16[r][:] = fp16( dinv[r] * (A[r][:] @ W) )
//    128x128 tile, 8x8 per thread, BK=32, A staged transposed in LDS.
__global__ __launch_bounds__(256, 2) void gemm_scale_kernel(const float* __restrict__ A,
                                                            const float* __restrict__ W,
                                                            const float* __restrict__ dinv,
                                                            __half* __restrict__ out16, int M) {
    __shared__ float sAT[32][132];
    __shared__ float sW[32][132];
    int tid = threadIdx.x;
    int row0 = blockIdx.x * 128;
    int ty = tid >> 4, tx = tid & 15;
    int r0 = ty * 8;
    int cl = tx * 4;
    int ch = 64 + tx * 4;

    float acc[8][8];
#pragma unroll
    for (int i = 0; i < 8; ++i)
#pragma unroll
        for (int j = 0; j < 8; ++j) acc[i][j] = 0.f;

    for (int kc = 0; kc < 128; kc += 32) {
#pragma unroll
        for (int p = 0; p < 4; ++p) {
            int idx = tid + p * 256;
            int k = idx >> 5, c4 = idx & 31;
            float4 v = *(const float4*)(W + (size_t)(kc + k) * 128 + c4 * 4);
            *(float4*)&sW[k][c4 * 4] = v;
        }
#pragma unroll
        for (int p = 0; p < 4; ++p) {
            int idx = tid + p * 256;
            int r = idx >> 3, c4 = idx & 7;
            float4 v = make_float4(0.f, 0.f, 0.f, 0.f);
            if (row0 + r < M) v = *(const float4*)(A + (size_t)(row0 + r) * 128 + kc + c4 * 4);
            sAT[c4 * 4 + 0][r] = v.x;
            sAT[c4 * 4 + 1][r] = v.y;
            sAT[c4 * 4 + 2][r] = v.z;
            sAT[c4 * 4 + 3][r] = v.w;
        }
        __syncthreads();

#pragma unroll 4
        for (int k = 0; k < 32; ++k) {
            float4 a0 = *(float4*)&sAT[k][r0];
            float4 a1 = *(float4*)&sAT[k][r0 + 4];
            float4 w0 = *(float4*)&sW[k][cl];
            float4 w1 = *(float4*)&sW[k][ch];
            float a[8] = {a0.x, a0.y, a0.z, a0.w, a1.x, a1.y, a1.z, a1.w};
            float w[8] = {w0.x, w0.y, w0.z, w0.w, w1.x, w1.y, w1.z, w1.w};
#pragma unroll
            for (int i = 0; i < 8; ++i)
#pragma unroll
                for (int j = 0; j < 8; ++j)
                    acc[i][j] += a[i] * w[j];
        }
        __syncthreads();
    }

#pragma unroll
    for (int i = 0; i < 8; ++i) {
        int r = row0 + r0 + i;
        if (r < M) {
            float dv = dinv[r];
            __half2 h0 = __floats2half2_rn(acc[i][0] * dv, acc[i][1] * dv);
            __half2 h1 = __floats2half2_rn(acc[i][2] * dv, acc[i][3] * dv);
            __half2 h2 = __floats2half2_rn(acc[i][4] * dv, acc[i][5] * dv);
            __half2 h3 = __floats2half2_rn(acc[i][6] * dv, acc[i][7] * dv);
            float2 plo, phi;
            ((__half2*)&plo)[0] = h0; ((__half2*)&plo)[1] = h1;
            ((__half2*)&phi)[0] = h2; ((__half2*)&phi)[1] = h3;
            *(float2*)(out16 + (size_t)r * 128 + cl) = plo;
            *(float2*)(out16 + (size_t)r * 128 + ch) = phi;
        }
    }
}

// 6) aggregation: out[v][:] = relu(dinv[v] * sum_{s in N(v)} hw16[s][:] + b)
//    fp16 gather (8B/lane), fp32 accumulate. 4-deep edge unroll.
__global__ __launch_bounds__(256) void aggregate_kernel(const __half* __restrict__ hw,
                                                        const int* __restrict__ row_ptr,
                                                        const int* __restrict__ col,
                                                        const float* __restrict__ dinv,
                                                        const float* __restrict__ bias,
                                                        float* __restrict__ out, int n) {
    int tid = threadIdx.x;
    int v = blockIdx.x * 8 + (tid >> 5);
    if (v >= n) return;
    int j = (tid & 31) * 4;
    int p0 = row_ptr[v], p1 = row_ptr[v + 1];
    float4 acc = make_float4(0.f, 0.f, 0.f, 0.f);
    int p = p0;
    for (; p + 3 < p1; p += 4) {
        int s0 = col[p], s1 = col[p + 1], s2 = col[p + 2], s3 = col[p + 3];
        float2 r0 = *(const float2*)(hw + (size_t)s0 * 128 + j);
        float2 r1 = *(const float2*)(hw + (size_t)s1 * 128 + j);
        float2 r2 = *(const float2*)(hw + (size_t)s2 * 128 + j);
        float2 r3 = *(const float2*)(hw + (size_t)s3 * 128 + j);
        float2 a0 = __half22float2(((__half2*)&r0)[0]), a1 = __half22float2(((__half2*)&r0)[1]);
        float2 b0 = __half22float2(((__half2*)&r1)[0]), b1 = __half22float2(((__half2*)&r1)[1]);
        float2 c0 = __half22float2(((__half2*)&r2)[0]), c1 = __half22float2(((__half2*)&r2)[1]);
        float2 d0 = __half22float2(((__half2*)&r3)[0]), d1 = __half22float2(((__half2*)&r3)[1]);
        acc.x += (a0.x + b0.x) + (c0.x + d0.x);
        acc.y += (a0.y + b0.y) + (c0.y + d0.y);
        acc.z += (a1.x + b1.x) + (c1.x + d1.x);
        acc.w += (a1.y + b1.y) + (c1.y + d1.y);
    }
    for (; p < p1; ++p) {
        int s0 = col[p];
        float2 r0 = *(const float2*)(hw + (size_t)s0 * 128 + j);
        float2 a0 = __half22float2(((__half2*)&r0)[0]), a1 = __half22float2(((__half2*)&r0)[1]);
        acc.x += a0.x; acc.y += a0.y; acc.z += a1.x; acc.w += a1.y;
    }
    float dv = dinv[v];
    float4 bb = *(const float4*)(bias + j);
    float4 o;
    o.x = fmaxf(acc.x * dv + bb.x, 0.f);
    o.y = fmaxf(acc.y * dv + bb.y, 0.f);
    o.z = fmaxf(acc.z * dv + bb.z, 0.f);
    o.w = fmaxf(acc.w * dv + bb.w, 0.f);
    *(float4*)(out + (size_t)v * 128 + j) = o;
}

// 7) graph boundary detection (batch sorted)
__global__ void boundary_kernel(const int* __restrict__ batch, int* __restrict__ start, int n) {
    int i = blockIdx.x * 256 + threadIdx.x;
    if (i >= n) return;
    int b = batch[i];
    int pb = (i > 0) ? batch[i - 1] : -1;
    if (b != pb) {
        for (int g = pb + 1; g <= b; ++g) start[g] = i;
    }
    if (i == n - 1) {
        for (int g = b + 1; g <= N_GRAPHS; ++g) start[g] = n;
    }
}

// 8) pooled mean per graph
__global__ __launch_bounds__(256) void pool_reduce_kernel(const float* __restrict__ h,
                                                          const int* __restrict__ start,
                                                          float* __restrict__ pooled) {
    __shared__ float part[8][128];
    int g = blockIdx.x;
    int s = start[g], e = start[g + 1];
    int tid = threadIdx.x;
    int grp = tid >> 5;
    int j = (tid & 31) * 4;
    float4 acc = make_float4(0.f, 0.f, 0.f, 0.f);
    for (int v = s + grp; v < e; v += 8) {
        float4 a = *(const float4*)(h + (size_t)v * 128 + j);
        acc.x += a.x; acc.y += a.y; acc.z += a.z; acc.w += a.w;
    }
    *(float4*)&part[grp][j] = acc;
    __syncthreads();
    if (tid < 128) {
        float sum = 0.f;
#pragma unroll
        for (int k = 0; k < 8; ++k) sum += part[k][tid];
        int cntv = e - s; if (cntv < 1) cntv = 1;
        pooled[g * 128 + tid] = sum / (float)cntv;
    }
}

// 9) final MLP
__global__ __launch_bounds__(256) void mlp_kernel(const float* __restrict__ pooled_g,
                                                  const float* __restrict__ W1,
                                                  const float* __restrict__ b1,
                                                  const float* __restrict__ W2,
                                                  const float* __restrict__ b2,
                                                  float* __restrict__ out) {
    __shared__ float pooled[64][128];
    __shared__ float h1[64][64];
    int tid = threadIdx.x;
    for (int i = tid; i < 64 * 128; i += 256) pooled[i >> 7][i & 127] = pooled_g[i];
    __syncthreads();
    for (int i = tid; i < 64 * 64; i += 256) {
        int g = i >> 6, j = i & 63;
        float acc = b1[j];
        for (int k = 0; k < 128; ++k) acc += pooled[g][k] * W1[k * 64 + j];
        h1[g][j] = fmaxf(acc, 0.f);
    }
    __syncthreads();
    if (tid < 128) {
        int g = tid >> 1, c = tid & 1;
        float acc = b2[c];
        for (int jj = 0; jj < 64; ++jj) acc += h1[g][jj] * W2[jj * 2 + c];
        out[tid] = acc;
    }
}

// ---------------------------------------------------------------------------
extern "C" void kernel_launch(void* const* d_in, const int* in_sizes, int n_in,
                              void* d_out, int out_size, void* d_ws, size_t ws_size,
                              hipStream_t stream) {
    const float* x    = (const float*)d_in[0];
    const int*   ei   = (const int*)d_in[1];
    const int*   batch= (const int*)d_in[2];
    const float* W0   = (const float*)d_in[3];
    const float* b0   = (const float*)d_in[4];
    const float* Ws   = (const float*)d_in[5];
    const float* bs   = (const float*)d_in[6];
    const float* W1   = (const float*)d_in[7];
    const float* b1   = (const float*)d_in[8];
    const float* W2   = (const float*)d_in[9];
    const float* b2   = (const float*)d_in[10];
    float* out = (float*)d_out;

    const int n  = in_sizes[0] / HID;      // 50000
    const int E  = in_sizes[1] / 2;        // 800000
    const int EN = E + n;                  // 850000
    const int* src = ei;
    const int* dst = ei + E;
    const int nb = (n + 255) / 256;        // 196

    char* ws = (char*)d_ws;
    size_t off = 0;
    auto alloc = [&](size_t bytes) { void* p = ws + off; off = (off + bytes + 255) & ~(size_t)255; return p; };
    float*  bufA   = (float*) alloc((size_t)n * HID * 4);   // h (fp32)
    __half* hw16   = (__half*)alloc((size_t)n * HID * 2);   // gemm output (fp16)
    float*  dinv   = (float*) alloc((size_t)n * 4);
    int*    row_ptr= (int*)   alloc((size_t)(n + 1) * 4);
    int*    cursor = (int*)   alloc((size_t)n * 4);
    int*    deg    = (int*)   alloc((size_t)n * 4);
    int*    col    = (int*)   alloc((size_t)EN * 4);
    int*    bsum   = (int*)   alloc((size_t)nb * 4);
    int*    boff   = (int*)   alloc((size_t)nb * 4);
    int*    gstart = (int*)   alloc((N_GRAPHS + 1) * 4);
    float*  pooled = (float*) alloc(N_GRAPHS * 128 * 4);
    (void)ws_size; (void)n_in; (void)out_size;

    // --- build normalized CSR ---
    init_deg_kernel<<<nb, 256, 0, stream>>>(deg, n);
    count_kernel<<<(E + 255) / 256, 256, 0, stream>>>(dst, deg, E);
    scan_partial_kernel<<<nb, 256, 0, stream>>>(deg, bsum, n);
    scan_bsum_kernel<<<1, 256, 0, stream>>>(bsum, boff, row_ptr, nb, n);
    scan_emit_kernel<<<nb, 256, 0, stream>>>(deg, boff, row_ptr, cursor, dinv, n);
    fill_kernel<<<(EN + 255) / 256, 256, 0, stream>>>(src, dst, cursor, col, E, EN);
    boundary_kernel<<<nb, 256, 0, stream>>>(batch, gstart, n);

    const int gemm_grid = (n + 127) / 128;
    const int node_grid = (n + 7) / 8;

    // --- layer 0 ---
    gemm_scale_kernel<<<gemm_grid, 256, 0, stream>>>(x, W0, dinv, hw16, n);
    aggregate_kernel<<<node_grid, 256, 0, stream>>>(hw16, row_ptr, col, dinv, b0, bufA, n);
    // --- layers 1..3 ---
    for (int l = 0; l < 3; ++l) {
        gemm_scale_kernel<<<gemm_grid, 256, 0, stream>>>(bufA, Ws + (size_t)l * HID * HID, dinv, hw16, n);
        aggregate_kernel<<<node_grid, 256, 0, stream>>>(hw16, row_ptr, col, dinv, bs + (size_t)l * HID, bufA, n);
    }

    // --- pooling + MLP ---
    pool_reduce_kernel<<<N_GRAPHS, 256, 0, stream>>>(bufA, gstart, pooled);
    mlp_kernel<<<1, 256, 0, stream>>>(pooled, W1, b1, W2, b2, out);
}